// Round 16
// baseline (128.440 us; speedup 1.0000x reference)
//
#include <hip/hip_runtime.h>
#include <stdint.h>

#define D_IN 2048
#define D_H  512

typedef __attribute__((ext_vector_type(4)))  int i32x4;
typedef __attribute__((ext_vector_type(16))) int i32x16;

// ======================= SPLIT PATH =======================
// Bit conventions (both sides must agree):
//   X-bit word (mb, q, c, r): bit j = sign(X[mb*64+r][256*q + 4*j + c])
//   A-frag (s, ah) slot p     -> physical k K(s,ah,p) =
//       256*(s>>3) + 4*(32*(s&1) + 16*ah + p) + ((s>>1)&3)
//   (a bijection onto [0,2048) over s=0..63, ah=0..1, p=0..15)

// --- pack W in permuted frag order: Wf[s][t][l][16] byte p = sign W[K][n] ---
__global__ __launch_bounds__(1024) void pack_wt_perm_kernel(
    const float* __restrict__ W, char* __restrict__ Wf) {
  const int s = blockIdx.x;          // 0..63
  const int t = threadIdx.x >> 6;    // 0..15
  const int l = threadIdx.x & 63;
  const int n  = t * 32 + (l & 31);
  const int ah = l >> 5;
  uint wq[4];
#pragma unroll
  for (int qd = 0; qd < 4; ++qd) {
    uint w = 0x01010101u;
#pragma unroll
    for (int j = 0; j < 4; ++j) {
      const int p = 4 * qd + j;
      const int k = (s >> 3) * 256 + ((s & 1) * 32 + ah * 16 + p) * 4 + ((s >> 1) & 3);
      uint bits = __float_as_uint(W[(size_t)k * D_H + n]);
      w ^= ((uint)((int)bits >> 31)) & (0xFEu << (8 * j));
    }
    wq[qd] = w;
  }
  *(uint4*)(Wf + ((size_t)(s * 16 + t) * 64 + l) * 16) =
      make_uint4(wq[0], wq[1], wq[2], wq[3]);
}

// --- pack X signs to bits: pure stream, no LDS, no barriers ---
__global__ __launch_bounds__(256) void pack_x_kernel(
    const float* __restrict__ X, unsigned long long* __restrict__ Xb) {
  const int l  = threadIdx.x & 63;
  const int wv = threadIdx.x >> 6;             // 0..3
  const int mb = blockIdx.x >> 2;
  const int r0 = (blockIdx.x & 3) * 16 + wv * 4;  // rows (mb-relative)
  unsigned long long* base = Xb + (size_t)mb * 2048;  // [q8][c4][r64] u64

  for (int rr = 0; rr < 4; ++rr) {
    const int r = r0 + rr;
    const float4* Xr = (const float4*)(X + ((size_t)mb * 64 + r) * D_IN);
#pragma unroll
    for (int q = 0; q < 8; ++q) {
      float4 v = Xr[q * 64 + l];                 // 1KB contiguous per instr
      unsigned long long b0 = __ballot(v.x < 0.0f);
      unsigned long long b1 = __ballot(v.y < 0.0f);
      unsigned long long b2 = __ballot(v.z < 0.0f);
      unsigned long long b3 = __ballot(v.w < 0.0f);
      if (l == 0) {
        base[q * 256 + 0 * 64 + r] = b0;
        base[q * 256 + 1 * 64 + r] = b1;
        base[q * 256 + 2 * 64 + r] = b2;
        base[q * 256 + 3 * 64 + r] = b3;
      }
    }
  }
}

// 16 sign bits -> 16 i8 of +1/-1 (byte p = bit p ? -1 : +1)
__device__ __forceinline__ i32x4 expand16(uint m) {
  i32x4 r;
#pragma unroll
  for (int j = 0; j < 4; ++j) {
    uint bq = (m >> (4 * j)) & 0xFu;
    uint spread = (bq * 0x00204081u) & 0x01010101u;  // bit i -> byte i LSB
    r[j] = (int)(0x01010101u | (spread * 0xFFu));    // byte: 0x01 or 0xFF
  }
  return r;
}

// --- GEMM from bits: no LDS, no barriers; manual depth-1 pipeline ---
// 1024 blocks x 512 thr. Block: (mb = bid>>1, colhalf = bid&1).
// Wave wv owns cols colhalf*256 + wv*32 .. +32 over all 64 rows of mb:
// per k-step 2 MFMA (row halves), acc = 2 x i32x16 (~80 VGPR total).
__global__ __launch_bounds__(512) void bgemm_bits_kernel(
    const unsigned long long* __restrict__ Xb, const char* __restrict__ Wf,
    const float* __restrict__ b, const float* __restrict__ beta,
    const float* __restrict__ mm, const float* __restrict__ mv,
    float* __restrict__ out) {
  const int tid = threadIdx.x;
  const int l   = tid & 63;
  const int wv  = tid >> 6;
  const int am  = l & 31;
  const int ah  = l >> 5;
  const int mb  = blockIdx.x >> 1;
  const size_t m0 = (size_t)mb * 64;
  const int colbase = (blockIdx.x & 1) * 256 + wv * 32;
  const int tile = colbase >> 5;   // 0..15

  const unsigned long long* xrow = Xb + (size_t)mb * 2048 + am;
  const char* Bbase = Wf + (size_t)tile * 1024 + (size_t)l * 16;
  const int sh0 = 16 * ah;        // s even
  const int sh1 = 32 + 16 * ah;   // s odd

  i32x16 acc0, acc1;
#pragma unroll
  for (int r = 0; r < 16; ++r) { acc0[r] = 0; acc1[r] = 0; }

  // prologue: set1 <- sp=0 (q=0,c=0; s=0,1)
  unsigned long long xa = xrow[0];
  unsigned long long xb = xrow[32];
  i32x4 B0 = *(const i32x4*)(Bbase);
  i32x4 B1 = *(const i32x4*)(Bbase + 16384);
  unsigned long long xa2, xb2;
  i32x4 B2, B3;

#pragma unroll 1
  for (int sp = 0; sp < 32; sp += 2) {
    {  // body A: prefetch sp+1 -> set2; compute sp from set1
      const int spn = sp + 1;
      const size_t xo = (size_t)(spn >> 2) * 256 + (size_t)(spn & 3) * 64;
      xa2 = xrow[xo];
      xb2 = xrow[xo + 32];
      B2 = *(const i32x4*)(Bbase + (size_t)(2 * spn) * 16384);
      B3 = *(const i32x4*)(Bbase + (size_t)(2 * spn + 1) * 16384);
      i32x4 a;
      a = expand16((uint)(xa >> sh0) & 0xFFFFu);
      acc0 = __builtin_amdgcn_mfma_i32_32x32x32_i8(a, B0, acc0, 0, 0, 0);
      a = expand16((uint)(xb >> sh0) & 0xFFFFu);
      acc1 = __builtin_amdgcn_mfma_i32_32x32x32_i8(a, B0, acc1, 0, 0, 0);
      a = expand16((uint)(xa >> sh1) & 0xFFFFu);
      acc0 = __builtin_amdgcn_mfma_i32_32x32x32_i8(a, B1, acc0, 0, 0, 0);
      a = expand16((uint)(xb >> sh1) & 0xFFFFu);
      acc1 = __builtin_amdgcn_mfma_i32_32x32x32_i8(a, B1, acc1, 0, 0, 0);
    }
    {  // body B: prefetch sp+2 -> set1; compute sp+1 from set2
      const int spn = sp + 2;
      if (spn < 32) {
        const size_t xo = (size_t)(spn >> 2) * 256 + (size_t)(spn & 3) * 64;
        xa = xrow[xo];
        xb = xrow[xo + 32];
        B0 = *(const i32x4*)(Bbase + (size_t)(2 * spn) * 16384);
        B1 = *(const i32x4*)(Bbase + (size_t)(2 * spn + 1) * 16384);
      }
      i32x4 a;
      a = expand16((uint)(xa2 >> sh0) & 0xFFFFu);
      acc0 = __builtin_amdgcn_mfma_i32_32x32x32_i8(a, B2, acc0, 0, 0, 0);
      a = expand16((uint)(xb2 >> sh0) & 0xFFFFu);
      acc1 = __builtin_amdgcn_mfma_i32_32x32x32_i8(a, B2, acc1, 0, 0, 0);
      a = expand16((uint)(xa2 >> sh1) & 0xFFFFu);
      acc0 = __builtin_amdgcn_mfma_i32_32x32x32_i8(a, B3, acc0, 0, 0, 0);
      a = expand16((uint)(xb2 >> sh1) & 0xFFFFu);
      acc1 = __builtin_amdgcn_mfma_i32_32x32x32_i8(a, B3, acc1, 0, 0, 0);
    }
  }

  // epilogue (verified layout): col = colbase+am, row = (r&3)+8*(r>>2)+4ah+32h
  const int rb = 4 * ah;
  const int c  = colbase + am;
  const float bb  = b[c];
  const float mmc = mm[c];
  const float bec = beta[c];
  const float inv = rsqrtf(mv[c] + 1e-3f);
#pragma unroll
  for (int h = 0; h < 2; ++h) {
    const i32x16 A = (h == 0) ? acc0 : acc1;
#pragma unroll
    for (int r = 0; r < 16; ++r) {
      const int row = (r & 3) + 8 * (r >> 2) + rb + 32 * h;
      out[(m0 + row) * D_H + c] = ((float)A[r] + bb - mmc) * inv + bec;
    }
  }
}

// ======================= FALLBACK (R15, passed) =======================
__device__ __forceinline__ void barrier_lgkm_only() {
  asm volatile("s_waitcnt lgkmcnt(0)" ::: "memory");
  __builtin_amdgcn_sched_barrier(0);
  __builtin_amdgcn_s_barrier();
  __builtin_amdgcn_sched_barrier(0);
}

__global__ __launch_bounds__(1024) void pack_wt_lin_kernel(
    const float* __restrict__ W, char* __restrict__ Wf) {
  const int s = blockIdx.x;
  const int t = threadIdx.x >> 6;
  const int l = threadIdx.x & 63;
  const int n = t * 32 + (l & 31);
  const int kbase = s * 32 + 16 * (l >> 5);
  uint wq[4];
#pragma unroll
  for (int q = 0; q < 4; ++q) {
    uint w = 0x01010101u;
#pragma unroll
    for (int j = 0; j < 4; ++j) {
      uint bits = __float_as_uint(W[(size_t)(kbase + 4 * q + j) * D_H + n]);
      w ^= ((uint)((int)bits >> 31)) & (0xFEu << (8 * j));
    }
    wq[q] = w;
  }
  *(uint4*)(Wf + ((size_t)(s * 16 + t) * 64 + l) * 16) =
      make_uint4(wq[0], wq[1], wq[2], wq[3]);
}

__device__ __forceinline__ uint pack4(float4 v) {
  uint w = 0x01010101u;
  w ^= ((uint)((int)__float_as_uint(v.x) >> 31)) & 0x000000FEu;
  w ^= ((uint)((int)__float_as_uint(v.y) >> 31)) & 0x0000FE00u;
  w ^= ((uint)((int)__float_as_uint(v.z) >> 31)) & 0x00FE0000u;
  w ^= ((uint)((int)__float_as_uint(v.w) >> 31)) & 0xFE000000u;
  return w;
}

__global__ __launch_bounds__(512) void bgemm_fused_kernel(
    const float* __restrict__ X, const char* __restrict__ Wf,
    const float* __restrict__ b, const float* __restrict__ beta,
    const float* __restrict__ mm, const float* __restrict__ mv,
    float* __restrict__ out) {
  __shared__ __align__(16) char XpL[2][8192];
  const int tid = threadIdx.x;
  const int l   = tid & 63;
  const int wv  = tid >> 6;
  const int am  = l & 31;
  const int ah  = l >> 5;
  const size_t m0 = (size_t)blockIdx.x * 64;
  const int colbase = wv * 64;
  const int r0 = tid >> 5;
  const int kw = tid & 31;
  const float* Xt = X + (m0 + r0) * D_IN + kw * 4;
  const int ws0 = r0 * 128 + (((kw >> 2) ^ (r0 & 7)) << 4) + (kw & 3) * 4;
  const int arow0 = am * 128;
  const int arow1 = arow0 + 32 * 128;
  const int akey  = am & 7;
  const char* Bb0 = Wf + (size_t)(2 * wv) * 1024 + (size_t)l * 16;
  const char* Bb1 = Bb0 + 1024;

  i32x16 acc00, acc01, acc10, acc11;
#pragma unroll
  for (int r = 0; r < 16; ++r) { acc00[r] = 0; acc01[r] = 0; acc10[r] = 0; acc11[r] = 0; }
  float4 vxa, vxb, vxc, vxd;
  vxa = *(const float4*)(Xt);
  vxb = *(const float4*)(Xt + 16 * D_IN);
  vxc = *(const float4*)(Xt + 32 * D_IN);
  vxd = *(const float4*)(Xt + 48 * D_IN);
  *(uint*)(XpL[0] + ws0)        = pack4(vxa);
  *(uint*)(XpL[0] + ws0 + 2048) = pack4(vxb);
  *(uint*)(XpL[0] + ws0 + 4096) = pack4(vxc);
  *(uint*)(XpL[0] + ws0 + 6144) = pack4(vxd);
  barrier_lgkm_only();

#pragma unroll 1
  for (int st = 0; st < 16; ++st) {
    const char* buf = &XpL[st & 1][0];
    const size_t so = (size_t)st * 65536;
    i32x4 B0a = *(const i32x4*)(Bb0 + so + 0 * 16384);
    i32x4 B0b = *(const i32x4*)(Bb1 + so + 0 * 16384);
    i32x4 B1a = *(const i32x4*)(Bb0 + so + 1 * 16384);
    i32x4 B1b = *(const i32x4*)(Bb1 + so + 1 * 16384);
    i32x4 B2a = *(const i32x4*)(Bb0 + so + 2 * 16384);
    i32x4 B2b = *(const i32x4*)(Bb1 + so + 2 * 16384);
    i32x4 B3a = *(const i32x4*)(Bb0 + so + 3 * 16384);
    i32x4 B3b = *(const i32x4*)(Bb1 + so + 3 * 16384);
    if (st + 1 < 16) {
      const float* xp = Xt + (st + 1) * 128;
      vxa = *(const float4*)(xp);
      vxb = *(const float4*)(xp + 16 * D_IN);
      vxc = *(const float4*)(xp + 32 * D_IN);
      vxd = *(const float4*)(xp + 48 * D_IN);
    }
    {
      i32x4 a0 = *(const i32x4*)(buf + arow0 + (((0 + ah) ^ akey) << 4));
      i32x4 a1 = *(const i32x4*)(buf + arow1 + (((0 + ah) ^ akey) << 4));
      acc00 = __builtin_amdgcn_mfma_i32_32x32x32_i8(a0, B0a, acc00, 0, 0, 0);
      acc10 = __builtin_amdgcn_mfma_i32_32x32x32_i8(a1, B0a, acc10, 0, 0, 0);
      acc01 = __builtin_amdgcn_mfma_i32_32x32x32_i8(a0, B0b, acc01, 0, 0, 0);
      acc11 = __builtin_amdgcn_mfma_i32_32x32x32_i8(a1, B0b, acc11, 0, 0, 0);
    }
    {
      i32x4 a0 = *(const i32x4*)(buf + arow0 + (((2 + ah) ^ akey) << 4));
      i32x4 a1 = *(const i32x4*)(buf + arow1 + (((2 + ah) ^ akey) << 4));
      acc00 = __builtin_amdgcn_mfma_i32_32x32x32_i8(a0, B1a, acc00, 0, 0, 0);
      acc10 = __builtin_amdgcn_mfma_i32_32x32x32_i8(a1, B1a, acc10, 0, 0, 0);
      acc01 = __builtin_amdgcn_mfma_i32_32x32x32_i8(a0, B1b, acc01, 0, 0, 0);
      acc11 = __builtin_amdgcn_mfma_i32_32x32x32_i8(a1, B1b, acc11, 0, 0, 0);
    }
    {
      i32x4 a0 = *(const i32x4*)(buf + arow0 + (((4 + ah) ^ akey) << 4));
      i32x4 a1 = *(const i32x4*)(buf + arow1 + (((4 + ah) ^ akey) << 4));
      acc00 = __builtin_amdgcn_mfma_i32_32x32x32_i8(a0, B2a, acc00, 0, 0, 0);
      acc10 = __builtin_amdgcn_mfma_i32_32x32x32_i8(a1, B2a, acc10, 0, 0, 0);
      acc01 = __builtin_amdgcn_mfma_i32_32x32x32_i8(a0, B2b, acc01, 0, 0, 0);
      acc11 = __builtin_amdgcn_mfma_i32_32x32x32_i8(a1, B2b, acc11, 0, 0, 0);
    }
    {
      i32x4 a0 = *(const i32x4*)(buf + arow0 + (((6 + ah) ^ akey) << 4));
      i32x4 a1 = *(const i32x4*)(buf + arow1 + (((6 + ah) ^ akey) << 4));
      acc00 = __builtin_amdgcn_mfma_i32_32x32x32_i8(a0, B3a, acc00, 0, 0, 0);
      acc10 = __builtin_amdgcn_mfma_i32_32x32x32_i8(a1, B3a, acc10, 0, 0, 0);
      acc01 = __builtin_amdgcn_mfma_i32_32x32x32_i8(a0, B3b, acc01, 0, 0, 0);
      acc11 = __builtin_amdgcn_mfma_i32_32x32x32_i8(a1, B3b, acc11, 0, 0, 0);
    }
    if (st + 1 < 16) {
      char* nbuf = &XpL[(st + 1) & 1][0];
      *(uint*)(nbuf + ws0)        = pack4(vxa);
      *(uint*)(nbuf + ws0 + 2048) = pack4(vxb);
      *(uint*)(nbuf + ws0 + 4096) = pack4(vxc);
      *(uint*)(nbuf + ws0 + 6144) = pack4(vxd);
    }
    barrier_lgkm_only();
  }

  const int rb = 4 * ah;
#pragma unroll
  for (int h = 0; h < 2; ++h) {
#pragma unroll
    for (int nt = 0; nt < 2; ++nt) {
      const i32x16 A = (h == 0) ? ((nt == 0) ? acc00 : acc01)
                                : ((nt == 0) ? acc10 : acc11);
      const int c = colbase + nt * 32 + am;
      const float bb  = b[c];
      const float mmc = mm[c];
      const float bec = beta[c];
      const float inv = rsqrtf(mv[c] + 1e-3f);
#pragma unroll
      for (int r = 0; r < 16; ++r) {
        const int row = (r & 3) + 8 * (r >> 2) + rb + 32 * h;
        out[(m0 + row) * D_H + c] = ((float)A[r] + bb - mmc) * inv + bec;
      }
    }
  }
}

extern "C" void kernel_launch(void* const* d_in, const int* in_sizes, int n_in,
                              void* d_out, int out_size, void* d_ws, size_t ws_size,
                              hipStream_t stream) {
  const float* X    = (const float*)d_in[0];  // [32768, 2048]
  const float* W    = (const float*)d_in[1];  // [2048, 512]
  const float* b    = (const float*)d_in[2];
  const float* beta = (const float*)d_in[3];
  const float* mm   = (const float*)d_in[4];
  const float* mv   = (const float*)d_in[5];
  float* out = (float*)d_out;                 // [32768, 512]

  const int M = in_sizes[0] / D_IN;           // 32768
  char* Wf = (char*)d_ws;                     // 1 MB

  const size_t need = (1u << 20) + (size_t)(M / 64) * 16384;  // Wf + Xb (9 MB)
  if (ws_size >= need) {
    unsigned long long* Xb = (unsigned long long*)(Wf + (1u << 20));
    pack_wt_perm_kernel<<<dim3(64), dim3(1024), 0, stream>>>(W, Wf);
    pack_x_kernel<<<dim3(M / 16), dim3(256), 0, stream>>>(X, Xb);
    bgemm_bits_kernel<<<dim3(M / 32), dim3(512), 0, stream>>>(Xb, Wf, b, beta,
                                                              mm, mv, out);
  } else {
    pack_wt_lin_kernel<<<dim3(64), dim3(1024), 0, stream>>>(W, Wf);
    bgemm_fused_kernel<<<dim3(M / 64), dim3(512), 0, stream>>>(X, Wf, b, beta,
                                                               mm, mv, out);
  }
}

// Round 17
// 88.766 us; speedup vs baseline: 1.4470x; 1.4470x over previous
//
#include <hip/hip_runtime.h>
#include <stdint.h>

#define D_IN 2048
#define D_H  512
#define BM   64
#define NST  16   // stages of 128 k

typedef __attribute__((ext_vector_type(4)))  int i32x4;
typedef __attribute__((ext_vector_type(16))) int i32x16;

// Wfrag[sg][t][l][16] : byte j = sign(W[sg*32 + 16*(l>>5) + j][t*32 + (l&31)])
// -> every GEMM B-load is 64 lanes x 16B = 1KB contiguous.
__global__ __launch_bounds__(1024) void pack_wt_kernel(
    const float* __restrict__ W, char* __restrict__ Wf) {
  const int s = blockIdx.x;          // 0..63  (k-step)
  const int t = threadIdx.x >> 6;    // 0..15  (col tile)
  const int l = threadIdx.x & 63;    // lane
  const int n = t * 32 + (l & 31);
  const int kbase = s * 32 + 16 * (l >> 5);
  uint wq[4];
#pragma unroll
  for (int q = 0; q < 4; ++q) {
    uint w = 0x01010101u;  // +1 bytes; negative -> XOR 0xFE -> 0xFF (-1)
#pragma unroll
    for (int j = 0; j < 4; ++j) {
      uint bits = __float_as_uint(W[(size_t)(kbase + 4 * q + j) * D_H + n]);
      w ^= ((uint)((int)bits >> 31)) & (0xFEu << (8 * j));
    }
    wq[q] = w;
  }
  *(uint4*)(Wf + ((size_t)(s * 16 + t) * 64 + l) * 16) =
      make_uint4(wq[0], wq[1], wq[2], wq[3]);
}

__device__ __forceinline__ uint pack4(float4 v) {
  uint w = 0x01010101u;
  w ^= ((uint)((int)__float_as_uint(v.x) >> 31)) & 0x000000FEu;
  w ^= ((uint)((int)__float_as_uint(v.y) >> 31)) & 0x0000FE00u;
  w ^= ((uint)((int)__float_as_uint(v.z) >> 31)) & 0x00FE0000u;
  w ^= ((uint)((int)__float_as_uint(v.w) >> 31)) & 0xFE000000u;
  return w;
}

// Binary GEMM via v_mfma_i32_32x32x32_i8.  (R10 structure — best measured:
// 88.7 us total.)  Block: 512 thr / 8 waves, 64 rows x 512 cols. Wave wv
// owns ALL 64 rows x cols [64wv,64wv+64): per k-step 2 A-frags (row halves)
// x 2 B-frags -> 4 MFMA; acc = 4 x i32x16. Per stage (128 k): 8 B-loads
// (1KB contig, oldest in vmcnt) -> 4 X-loads (512B runs, youngest; depth-1
// prefetch) -> 4 k-steps {2 ds_read_b128, 4 MFMA} -> pack X -> 4 ds_write
// -> barrier. B-waits never drain the X prefetch (in-order vmcnt retire).
__global__ __launch_bounds__(512) void bgemm_kernel(
    const float* __restrict__ X, const char* __restrict__ Wf,
    const float* __restrict__ b, const float* __restrict__ beta,
    const float* __restrict__ mm, const float* __restrict__ mv,
    float* __restrict__ out) {
  __shared__ __align__(16) char XpL[2][8192];  // 2 x (64 rows x 128 k-bytes)

  const int tid = threadIdx.x;
  const int l   = tid & 63;
  const int wv  = tid >> 6;        // 0..7
  const int am  = l & 31;
  const int ah  = l >> 5;
  const size_t m0 = (size_t)blockIdx.x * BM;
  const int colbase = wv * 64;

  // X loader: thread -> rows r0+{0,16,32,48}, float4 index kw within slice
  const int r0 = tid >> 5;   // 0..15
  const int kw = tid & 31;   // 0..31
  const float* Xt = X + (m0 + r0) * D_IN + kw * 4;

  // LDS write byte offset for row r0 (rows +16i share the key: 16 = 0 mod 8)
  const int ws0 = r0 * 128 + (((kw >> 2) ^ (r0 & 7)) << 4) + (kw & 3) * 4;

  // LDS read: row halves at am and am+32 (same key am&7)
  const int arow0 = am * 128;
  const int arow1 = arow0 + 32 * 128;
  const int akey  = am & 7;

  // B pointers: tiles 2wv, 2wv+1; load for (st,s') at + st*65536 + s'*16384
  const char* Bb0 = Wf + (size_t)(2 * wv) * 1024 + (size_t)l * 16;
  const char* Bb1 = Bb0 + 1024;

  i32x16 acc00, acc01, acc10, acc11;  // [rowhalf][tile]
#pragma unroll
  for (int r = 0; r < 16; ++r) { acc00[r] = 0; acc01[r] = 0; acc10[r] = 0; acc11[r] = 0; }

  float4 vxa, vxb, vxc, vxd;

  // ---- prologue: stage 0 loaded + packed directly ----
  vxa = *(const float4*)(Xt);
  vxb = *(const float4*)(Xt + 16 * D_IN);
  vxc = *(const float4*)(Xt + 32 * D_IN);
  vxd = *(const float4*)(Xt + 48 * D_IN);
  *(uint*)(XpL[0] + ws0)        = pack4(vxa);
  *(uint*)(XpL[0] + ws0 + 2048) = pack4(vxb);
  *(uint*)(XpL[0] + ws0 + 4096) = pack4(vxc);
  *(uint*)(XpL[0] + ws0 + 6144) = pack4(vxd);
  __syncthreads();

#pragma unroll 1
  for (int st = 0; st < NST; ++st) {
    const char* buf = &XpL[st & 1][0];
    const size_t so = (size_t)st * 65536;

    // 1) all 8 B-loads (oldest in vmcnt; waits on them never touch X)
    i32x4 B0a = *(const i32x4*)(Bb0 + so + 0 * 16384);
    i32x4 B0b = *(const i32x4*)(Bb1 + so + 0 * 16384);
    i32x4 B1a = *(const i32x4*)(Bb0 + so + 1 * 16384);
    i32x4 B1b = *(const i32x4*)(Bb1 + so + 1 * 16384);
    i32x4 B2a = *(const i32x4*)(Bb0 + so + 2 * 16384);
    i32x4 B2b = *(const i32x4*)(Bb1 + so + 2 * 16384);
    i32x4 B3a = *(const i32x4*)(Bb0 + so + 3 * 16384);
    i32x4 B3b = *(const i32x4*)(Bb1 + so + 3 * 16384);

    // 2) X for stage st+1 (youngest; consumed at stage end)
    if (st + 1 < NST) {
      const float* xp = Xt + (st + 1) * 128;
      vxa = *(const float4*)(xp);
      vxb = *(const float4*)(xp + 16 * D_IN);
      vxc = *(const float4*)(xp + 32 * D_IN);
      vxd = *(const float4*)(xp + 48 * D_IN);
    }

    // 3) 4 k-steps
    {
      i32x4 a0 = *(const i32x4*)(buf + arow0 + (((0 + ah) ^ akey) << 4));
      i32x4 a1 = *(const i32x4*)(buf + arow1 + (((0 + ah) ^ akey) << 4));
      acc00 = __builtin_amdgcn_mfma_i32_32x32x32_i8(a0, B0a, acc00, 0, 0, 0);
      acc10 = __builtin_amdgcn_mfma_i32_32x32x32_i8(a1, B0a, acc10, 0, 0, 0);
      acc01 = __builtin_amdgcn_mfma_i32_32x32x32_i8(a0, B0b, acc01, 0, 0, 0);
      acc11 = __builtin_amdgcn_mfma_i32_32x32x32_i8(a1, B0b, acc11, 0, 0, 0);
    }
    {
      i32x4 a0 = *(const i32x4*)(buf + arow0 + (((2 + ah) ^ akey) << 4));
      i32x4 a1 = *(const i32x4*)(buf + arow1 + (((2 + ah) ^ akey) << 4));
      acc00 = __builtin_amdgcn_mfma_i32_32x32x32_i8(a0, B1a, acc00, 0, 0, 0);
      acc10 = __builtin_amdgcn_mfma_i32_32x32x32_i8(a1, B1a, acc10, 0, 0, 0);
      acc01 = __builtin_amdgcn_mfma_i32_32x32x32_i8(a0, B1b, acc01, 0, 0, 0);
      acc11 = __builtin_amdgcn_mfma_i32_32x32x32_i8(a1, B1b, acc11, 0, 0, 0);
    }
    {
      i32x4 a0 = *(const i32x4*)(buf + arow0 + (((4 + ah) ^ akey) << 4));
      i32x4 a1 = *(const i32x4*)(buf + arow1 + (((4 + ah) ^ akey) << 4));
      acc00 = __builtin_amdgcn_mfma_i32_32x32x32_i8(a0, B2a, acc00, 0, 0, 0);
      acc10 = __builtin_amdgcn_mfma_i32_32x32x32_i8(a1, B2a, acc10, 0, 0, 0);
      acc01 = __builtin_amdgcn_mfma_i32_32x32x32_i8(a0, B2b, acc01, 0, 0, 0);
      acc11 = __builtin_amdgcn_mfma_i32_32x32x32_i8(a1, B2b, acc11, 0, 0, 0);
    }
    {
      i32x4 a0 = *(const i32x4*)(buf + arow0 + (((6 + ah) ^ akey) << 4));
      i32x4 a1 = *(const i32x4*)(buf + arow1 + (((6 + ah) ^ akey) << 4));
      acc00 = __builtin_amdgcn_mfma_i32_32x32x32_i8(a0, B3a, acc00, 0, 0, 0);
      acc10 = __builtin_amdgcn_mfma_i32_32x32x32_i8(a1, B3a, acc10, 0, 0, 0);
      acc01 = __builtin_amdgcn_mfma_i32_32x32x32_i8(a0, B3b, acc01, 0, 0, 0);
      acc11 = __builtin_amdgcn_mfma_i32_32x32x32_i8(a1, B3b, acc11, 0, 0, 0);
    }

    // 4) pack + write next stage's A tile
    if (st + 1 < NST) {
      char* nbuf = &XpL[(st + 1) & 1][0];
      *(uint*)(nbuf + ws0)        = pack4(vxa);
      *(uint*)(nbuf + ws0 + 2048) = pack4(vxb);
      *(uint*)(nbuf + ws0 + 4096) = pack4(vxc);
      *(uint*)(nbuf + ws0 + 6144) = pack4(vxd);
    }
    __syncthreads();
  }

  // ---- epilogue: out = (dot + b - mean) * rsqrt(var+eps) + beta ----
  // D layout (verified): col = tile base + am, row = (r&3)+8*(r>>2)+4*ah (+32h)
  const int rb = 4 * ah;
#pragma unroll
  for (int h = 0; h < 2; ++h) {
#pragma unroll
    for (int nt = 0; nt < 2; ++nt) {
      const i32x16 A = (h == 0) ? ((nt == 0) ? acc00 : acc01)
                                : ((nt == 0) ? acc10 : acc11);
      const int c = colbase + nt * 32 + am;
      const float bb  = b[c];
      const float mmc = mm[c];
      const float bec = beta[c];
      const float inv = rsqrtf(mv[c] + 1e-3f);
#pragma unroll
      for (int r = 0; r < 16; ++r) {
        const int row = (r & 3) + 8 * (r >> 2) + rb + 32 * h;
        out[(m0 + row) * D_H + c] = ((float)A[r] + bb - mmc) * inv + bec;
      }
    }
  }
}

extern "C" void kernel_launch(void* const* d_in, const int* in_sizes, int n_in,
                              void* d_out, int out_size, void* d_ws, size_t ws_size,
                              hipStream_t stream) {
  const float* X    = (const float*)d_in[0];  // [32768, 2048]
  const float* W    = (const float*)d_in[1];  // [2048, 512]
  const float* b    = (const float*)d_in[2];  // [512]
  const float* beta = (const float*)d_in[3];  // [512]
  const float* mm   = (const float*)d_in[4];  // [512]
  const float* mv   = (const float*)d_in[5];  // [512]
  float* out = (float*)d_out;                 // [32768, 512]

  char* Wf = (char*)d_ws;  // frag-ordered W signs, 1 MB

  pack_wt_kernel<<<dim3(D_IN / 32), dim3(1024), 0, stream>>>(W, Wf);

  const int M = in_sizes[0] / D_IN;  // 32768
  bgemm_kernel<<<dim3(M / BM), dim3(512), 0, stream>>>(X, Wf, b, beta, mm, mv, out);
}